// Round 4
// baseline (307.307 us; speedup 1.0000x reference)
//
#include <hip/hip_runtime.h>
#include <hip/hip_bf16.h>

typedef unsigned short u16;
typedef unsigned int   u32;
typedef __attribute__((ext_vector_type(8))) short short8;   // 8 bf16 (4 VGPRs)
typedef __attribute__((ext_vector_type(4))) float f32x4;

#define T_ROWS   131072
#define L_CHUNK  16
#define WARM     8             // rho<=0.34 -> 0.34^8 * 0.3 ~ 5e-5 boundary error
#define NCHUNK   (T_ROWS / L_CHUNK)   // 8192

// ws layout (float offsets)
#define WS_SUM   0             // 256 f
#define WS_SQ    256           // 256 f
#define WS_CJ    512           // 64 f  (b1 + shift@W1 folded)
#define WS_WEF   576           // 8192 u32: We bf16 in MFMA B-frag order [ks*4+nt][lane][j(8)]
#define WS_PRE_BYTES ((size_t)(WS_WEF + 8192) * 4)            // 35072 B
#define WS_NEED  (WS_PRE_BYTES + (size_t)T_ROWS * 64 * 2)     // + pre1t bf16 ~16.8 MB

__device__ __forceinline__ u16 f2bf(float f) {   // RNE float->bf16
  u32 u = __float_as_uint(f);
  u += 0x7FFFu + ((u >> 16) & 1u);
  return (u16)(u >> 16);
}

template <int CTRL>
__device__ __forceinline__ float dpp_take(float v) {
  return __int_as_float(
      __builtin_amdgcn_update_dpp(0, __float_as_int(v), CTRL, 0xF, 0xF, true));
}
__device__ __forceinline__ float swz_xor16(float v) {   // xor16 within 32-lane groups
  return __int_as_float(__builtin_amdgcn_ds_swizzle(__float_as_int(v), 0x401F));
}

__global__ void k_zero(float* ws) { ws[threadIdx.x] = 0.0f; }   // <<<1,512>>>

__global__ void k_sentinel(float* out) { out[threadIdx.x] = 12345.0f; }

// ---- column mean / sumsq over x[131072][256], grid 1024 x 256 thr ----
__global__ __launch_bounds__(256) void k_stats(const float* __restrict__ x,
                                               float* __restrict__ ws) {
  __shared__ float lsum[1024];
  __shared__ float lsq[1024];
  const int tid = threadIdx.x;
  const int lane = tid & 63;
  const int w = tid >> 6;
  const int c = lane * 4;
  float s0 = 0, s1 = 0, s2 = 0, s3 = 0;
  float q0 = 0, q1 = 0, q2 = 0, q3 = 0;
  const size_t rbase = (size_t)blockIdx.x * 128;
  for (int i = w; i < 128; i += 4) {
    const float4 v = *(const float4*)(x + (rbase + i) * 256 + c);
    s0 += v.x; s1 += v.y; s2 += v.z; s3 += v.w;
    q0 = fmaf(v.x, v.x, q0); q1 = fmaf(v.y, v.y, q1);
    q2 = fmaf(v.z, v.z, q2); q3 = fmaf(v.w, v.w, q3);
  }
  lsum[w * 256 + c + 0] = s0; lsum[w * 256 + c + 1] = s1;
  lsum[w * 256 + c + 2] = s2; lsum[w * 256 + c + 3] = s3;
  lsq [w * 256 + c + 0] = q0; lsq [w * 256 + c + 1] = q1;
  lsq [w * 256 + c + 2] = q2; lsq [w * 256 + c + 3] = q3;
  __syncthreads();
  const float ts = lsum[tid] + lsum[256 + tid] + lsum[512 + tid] + lsum[768 + tid];
  const float tq = lsq [tid] + lsq [256 + tid] + lsq [512 + tid] + lsq [768 + tid];
  atomicAdd(ws + WS_SUM + tid, ts);
  atomicAdd(ws + WS_SQ  + tid, tq);
}

// ---- fold BN into weights. Emits We = scale*W1[:256] in MFMA B-fragment order. ----
__global__ __launch_bounds__(256) void k_prep(const float* __restrict__ gamma,
                                              const float* __restrict__ beta,
                                              const float* __restrict__ W1,
                                              const float* __restrict__ b1,
                                              float* __restrict__ ws) {
  __shared__ float sScale[256];
  __shared__ float sShift[256];
  __shared__ float sCj[256];
  const int tid = threadIdx.x;
  const float inv = 1.0f / (float)T_ROWS;
  const float mean = ws[WS_SUM + tid] * inv;
  const float var  = ws[WS_SQ + tid] * inv - mean * mean;   // biased, as keras BN
  const float sc = gamma[tid] * rsqrtf(var + 1e-3f);
  const float sh = beta[tid] - mean * sc;
  sScale[tid] = sc;
  sShift[tid] = sh;
  __syncthreads();
  const int nt = tid >> 6;
  const int lane = tid & 63;
  const int m = lane & 15;
  const int q = lane >> 4;
  const int n = nt * 16 + m;
  u32* Wf = (u32*)(ws + WS_WEF);
#pragma unroll
  for (int ks = 0; ks < 8; ++ks) {
    uint4 pk;
    u32 w_[4];
#pragma unroll
    for (int jj = 0; jj < 4; ++jj) {
      const int k0 = ks * 32 + q * 8 + 2 * jj;
      const u32 lo = f2bf(sScale[k0]     * W1[(size_t)k0 * 64 + n]);
      const u32 hi = f2bf(sScale[k0 + 1] * W1[(size_t)(k0 + 1) * 64 + n]);
      w_[jj] = lo | (hi << 16);
    }
    pk.x = w_[0]; pk.y = w_[1]; pk.z = w_[2]; pk.w = w_[3];
    *(uint4*)(Wf + (size_t)((ks * 4 + nt) * 64 + lane) * 4) = pk;
  }
  // cj[j] = b1[j] + sum_c sShift[c]*W1[c][j], 4-way split over c then LDS combine
  const int j = tid & 63;
  const int part = tid >> 6;
  float p = (part == 0) ? b1[j] : 0.0f;
  for (int c = part * 64; c < part * 64 + 64; ++c)
    p = fmaf(sShift[c], W1[(size_t)c * 64 + j], p);
  sCj[tid] = p;
  __syncthreads();
  if (tid < 64)
    ws[WS_CJ + tid] = sCj[tid] + sCj[64 + tid] + sCj[128 + tid] + sCj[192 + tid];
}

// ---- pre1t = bf16( x @ We + cj ), chunk-transposed: pre1t[p][j][t] (p=row/16).
//      grid 2048 x 256 thr; wave w handles rows blk*64 + w*16 .. +15 = chunk p. ----
__global__ __launch_bounds__(256) void k_gemm(const float* __restrict__ x,
                                              const float* __restrict__ ws,
                                              u16* __restrict__ pre1t) {
  const int lane = threadIdx.x & 63;
  const int w = threadIdx.x >> 6;
  const int m = lane & 15;
  const int q = lane >> 4;
  const size_t r0 = (size_t)blockIdx.x * 64 + (size_t)w * 16;
  const size_t p = r0 >> 4;                       // chunk index
  const float* xr = x + (r0 + m) * 256 + q * 8;   // lane's A-frag source row/col
  const u32* Bf = (const u32*)(ws + WS_WEF);

  f32x4 acc[4];
#pragma unroll
  for (int nt = 0; nt < 4; ++nt) acc[nt] = (f32x4){0.f, 0.f, 0.f, 0.f};

#pragma unroll
  for (int ks = 0; ks < 8; ++ks) {
    const float4 xa = *(const float4*)(xr + ks * 32);
    const float4 xb = *(const float4*)(xr + ks * 32 + 4);
    union { short8 v; u32 u[4]; } A;
    A.u[0] = f2bf(xa.x) | ((u32)f2bf(xa.y) << 16);
    A.u[1] = f2bf(xa.z) | ((u32)f2bf(xa.w) << 16);
    A.u[2] = f2bf(xb.x) | ((u32)f2bf(xb.y) << 16);
    A.u[3] = f2bf(xb.z) | ((u32)f2bf(xb.w) << 16);
#pragma unroll
    for (int nt = 0; nt < 4; ++nt) {
      const short8 Bv = *(const short8*)(Bf + (size_t)((ks * 4 + nt) * 64 + lane) * 4);
      acc[nt] = __builtin_amdgcn_mfma_f32_16x16x32_bf16(A.v, Bv, acc[nt], 0, 0, 0);
    }
  }
  // C/D layout (m89): col = nt*16 + m, row-in-chunk = q*4 + reg.
  // Store transposed: pre1t[p*1024 + col*16 + (q*4..q*4+3)] as one 8-byte packed write.
#pragma unroll
  for (int nt = 0; nt < 4; ++nt) {
    const float c = ws[WS_CJ + nt * 16 + m];
    uint2 pk;
    pk.x = (u32)f2bf(acc[nt][0] + c) | ((u32)f2bf(acc[nt][1] + c) << 16);
    pk.y = (u32)f2bf(acc[nt][2] + c) | ((u32)f2bf(acc[nt][3] + c) << 16);
    *(uint2*)(pre1t + p * 1024 + (size_t)(nt * 16 + m) * 16 + q * 4) = pk;
  }
}

// ---- chunked scan, memory-free inner loop. 4 independent waves / block. ----
__global__ __launch_bounds__(256, 4) void k_scan(const u16* __restrict__ pre1t,
                                                 const float* __restrict__ W1,
                                                 const float* __restrict__ W2,
                                                 const float* __restrict__ b2,
                                                 const float* __restrict__ W3,
                                                 const float* __restrict__ b3,
                                                 float* __restrict__ out) {
  const int tid = threadIdx.x;
  const int lane = tid & 63;
  const int wv = tid >> 6;
  const int p = blockIdx.x * 4 + wv;            // chunk id
  const int m = lane & 31;
  const int half = lane >> 5;
  const int outStart = p * L_CHUNK;

  float Wh[8];
#pragma unroll
  for (int k = 0; k < 8; ++k) Wh[k] = W1[(256 + k) * 64 + lane];
  float W2r[32];
#pragma unroll
  for (int i = 0; i < 32; ++i) W2r[i] = W2[(32 * half + i) * 32 + m];
  const float b2r = b2[m];
  float W3r[8], b3r[8];
#pragma unroll
  for (int n = 0; n < 8; ++n) W3r[n] = W3[m * 8 + n];
#pragma unroll
  for (int n = 0; n < 8; ++n) b3r[n] = b3[n];

  __shared__ __align__(16) float lh1[4][64];

  // preload this lane's pre values: chunk p (16) + tail of chunk p-1 (8)
  const u16* base = pre1t + (size_t)p * 1024 + (size_t)lane * 16;
  const uint4 mv0 = *(const uint4*)(base);        // t 0..7
  const uint4 mv1 = *(const uint4*)(base + 8);    // t 8..15
  uint4 wv4 = make_uint4(0, 0, 0, 0);
  if (p > 0) wv4 = *(const uint4*)(base - 1024 + 8);   // prev chunk t 8..15
  const u32 preW[4] = {wv4.x, wv4.y, wv4.z, wv4.w};
  const u32 preM[8] = {mv0.x, mv0.y, mv0.z, mv0.w, mv1.x, mv1.y, mv1.z, mv1.w};

  float h[8];
#pragma unroll
  for (int n = 0; n < 8; ++n) h[n] = 0.0f;
  float osv[8];
#pragma unroll
  for (int n = 0; n < 8; ++n) osv[n] = 0.0f;

  auto step = [&](float pf, bool save, int slane) {
    float a0 = pf, a1 = 0.0f;
#pragma unroll
    for (int k = 0; k < 4; ++k) {                 // a = pre + Wh^T h (2 chains)
      a0 = fmaf(h[2 * k],     Wh[2 * k],     a0);
      a1 = fmaf(h[2 * k + 1], Wh[2 * k + 1], a1);
    }
    const float h1 = fmaxf(a0 + a1, 0.0f);
    // single-wave LDS round-trip: HW DS ops are in-order per wave; wave_barrier
    // pins compiler ordering. No __syncthreads -> no vmcnt drain, no wave coupling.
    __builtin_amdgcn_wave_barrier();
    lh1[wv][lane] = h1;
    __builtin_amdgcn_wave_barrier();
    const float4* qv = (const float4*)(lh1[wv] + half * 32);
    float c0 = 0, c1 = 0, c2 = 0, c3 = 0;
#pragma unroll
    for (int r = 0; r < 8; ++r) {                 // half-sum of h1@W2 column m
      const float4 v = qv[r];
      c0 = fmaf(v.x, W2r[4 * r + 0], c0);
      c1 = fmaf(v.y, W2r[4 * r + 1], c1);
      c2 = fmaf(v.z, W2r[4 * r + 2], c2);
      c3 = fmaf(v.w, W2r[4 * r + 3], c3);
    }
    const float part = (c0 + c1) + (c2 + c3);
    const float h2 = fmaxf(part + __shfl_xor(part, 32, 64) + b2r, 0.0f);
    float o[8];
#pragma unroll
    for (int n = 0; n < 8; ++n) o[n] = h2 * W3r[n];
#pragma unroll
    for (int n = 0; n < 8; ++n) o[n] += dpp_take<0xB1>(o[n]);   // quad_perm xor1
#pragma unroll
    for (int n = 0; n < 8; ++n) o[n] += dpp_take<0x4E>(o[n]);   // quad_perm xor2
#pragma unroll
    for (int n = 0; n < 8; ++n) o[n] += dpp_take<0x141>(o[n]);  // row_half_mirror (8)
#pragma unroll
    for (int n = 0; n < 8; ++n) o[n] += dpp_take<0x140>(o[n]);  // row_mirror (16)
#pragma unroll
    for (int n = 0; n < 8; ++n) o[n] += swz_xor16(o[n]);        // xor16 within 32
#pragma unroll
    for (int n = 0; n < 8; ++n) h[n] = o[n] + b3r[n];
    if (save) {
      const bool mine = (lane == slane);
#pragma unroll
      for (int n = 0; n < 8; ++n) osv[n] = mine ? h[n] : osv[n];
    }
  };

  if (p > 0) {
#pragma unroll
    for (int i = 0; i < 8; ++i) {
      const u32 wd = preW[i >> 1];
      const float pf = (i & 1) ? __uint_as_float(wd & 0xFFFF0000u)
                               : __uint_as_float(wd << 16);
      step(pf, false, -1);
    }
  }
#pragma unroll
  for (int u = 0; u < 16; ++u) {
    const u32 wd = preM[u >> 1];
    const float pf = (u & 1) ? __uint_as_float(wd & 0xFFFF0000u)
                             : __uint_as_float(wd << 16);
    step(pf, true, u);
  }

  if (lane < 16) {                                // coalesced epilogue store
    float4* dst = (float4*)(out + (size_t)(outStart + lane) * 8);
    dst[0] = make_float4(osv[0], osv[1], osv[2], osv[3]);
    dst[1] = make_float4(osv[4], osv[5], osv[6], osv[7]);
  }
}

extern "C" void kernel_launch(void* const* d_in, const int* in_sizes, int n_in,
                              void* d_out, int out_size, void* d_ws, size_t ws_size,
                              hipStream_t stream) {
  (void)in_sizes; (void)n_in; (void)out_size;
  const float* x     = (const float*)d_in[0];
  const float* gamma = (const float*)d_in[1];
  const float* beta  = (const float*)d_in[2];
  const float* W1    = (const float*)d_in[3];
  const float* b1    = (const float*)d_in[4];
  const float* W2    = (const float*)d_in[5];
  const float* b2    = (const float*)d_in[6];
  const float* W3    = (const float*)d_in[7];
  const float* b3    = (const float*)d_in[8];
  float* out = (float*)d_out;
  float* ws  = (float*)d_ws;
  u16* pre1t = (u16*)((char*)d_ws + WS_PRE_BYTES);

  if (ws_size < WS_NEED) {               // diagnosable failure: absmax ~12345
    k_sentinel<<<1, 64, 0, stream>>>(out);
    return;
  }
  k_zero <<<1,    512, 0, stream>>>(ws);
  k_stats<<<1024, 256, 0, stream>>>(x, ws);
  k_prep <<<1,    256, 0, stream>>>(gamma, beta, W1, b1, ws);
  k_gemm <<<2048, 256, 0, stream>>>(x, ws, pre1t);
  k_scan <<<NCHUNK / 4, 256, 0, stream>>>(pre1t, W1, W2, b2, W3, b3, out);
}

// Round 5
// 292.821 us; speedup vs baseline: 1.0495x; 1.0495x over previous
//
#include <hip/hip_runtime.h>
#include <hip/hip_bf16.h>

typedef unsigned short u16;
typedef unsigned int   u32;
typedef __attribute__((ext_vector_type(8))) short short8;   // 8 bf16 (4 VGPRs)
typedef __attribute__((ext_vector_type(4))) float f32x4;

#define T_ROWS   131072
#define L_CHUNK  32
#define WARM     8             // rho<=0.34 -> 0.34^8 * 0.3 ~ 5e-5 boundary error
#define NCHUNK   (T_ROWS / L_CHUNK)   // 4096

// ws layout (float offsets)
#define WS_SUM   0             // 256 f
#define WS_SQ    256           // 256 f
#define WS_CJ    512           // 64 f  (b1 + shift@W1 folded)
#define WS_WEF   576           // 8192 u32: We bf16 in MFMA B-frag order [ks*4+nt][lane][j(8)]
#define WS_PRE_BYTES ((size_t)(WS_WEF + 8192) * 4)            // 35072 B
#define WS_NEED  (WS_PRE_BYTES + (size_t)T_ROWS * 64 * 2)     // + pre1t bf16 ~16.8 MB

__device__ __forceinline__ u16 f2bf(float f) {   // RNE float->bf16
  u32 u = __float_as_uint(f);
  u += 0x7FFFu + ((u >> 16) & 1u);
  return (u16)(u >> 16);
}

template <int CTRL>
__device__ __forceinline__ float dpp_take(float v) {
  return __int_as_float(
      __builtin_amdgcn_update_dpp(0, __float_as_int(v), CTRL, 0xF, 0xF, true));
}
__device__ __forceinline__ float swz_xor16(float v) {   // xor16 within 32-lane groups
  return __int_as_float(__builtin_amdgcn_ds_swizzle(__float_as_int(v), 0x401F));
}

__global__ void k_zero(float* ws) { ws[threadIdx.x] = 0.0f; }   // <<<1,512>>>

__global__ void k_sentinel(float* out) { out[threadIdx.x] = 12345.0f; }

// ---- column mean / sumsq over x[131072][256], grid 1024 x 256 thr ----
__global__ __launch_bounds__(256) void k_stats(const float* __restrict__ x,
                                               float* __restrict__ ws) {
  __shared__ float lsum[1024];
  __shared__ float lsq[1024];
  const int tid = threadIdx.x;
  const int lane = tid & 63;
  const int w = tid >> 6;
  const int c = lane * 4;
  float s0 = 0, s1 = 0, s2 = 0, s3 = 0;
  float q0 = 0, q1 = 0, q2 = 0, q3 = 0;
  const size_t rbase = (size_t)blockIdx.x * 128;
#pragma unroll 4
  for (int i = w; i < 128; i += 4) {
    const float4 v = *(const float4*)(x + (rbase + i) * 256 + c);
    s0 += v.x; s1 += v.y; s2 += v.z; s3 += v.w;
    q0 = fmaf(v.x, v.x, q0); q1 = fmaf(v.y, v.y, q1);
    q2 = fmaf(v.z, v.z, q2); q3 = fmaf(v.w, v.w, q3);
  }
  lsum[w * 256 + c + 0] = s0; lsum[w * 256 + c + 1] = s1;
  lsum[w * 256 + c + 2] = s2; lsum[w * 256 + c + 3] = s3;
  lsq [w * 256 + c + 0] = q0; lsq [w * 256 + c + 1] = q1;
  lsq [w * 256 + c + 2] = q2; lsq [w * 256 + c + 3] = q3;
  __syncthreads();
  const float ts = lsum[tid] + lsum[256 + tid] + lsum[512 + tid] + lsum[768 + tid];
  const float tq = lsq [tid] + lsq [256 + tid] + lsq [512 + tid] + lsq [768 + tid];
  atomicAdd(ws + WS_SUM + tid, ts);
  atomicAdd(ws + WS_SQ  + tid, tq);
}

// ---- fold BN into weights. Emits We = scale*W1[:256] in MFMA B-frag order. 512 thr. ----
__global__ __launch_bounds__(512) void k_prep(const float* __restrict__ gamma,
                                              const float* __restrict__ beta,
                                              const float* __restrict__ W1,
                                              const float* __restrict__ b1,
                                              float* __restrict__ ws) {
  __shared__ float sScale[256];
  __shared__ float sShift[256];
  __shared__ float sCj[512];
  const int tid = threadIdx.x;
  if (tid < 256) {
    const float inv = 1.0f / (float)T_ROWS;
    const float mean = ws[WS_SUM + tid] * inv;
    const float var  = ws[WS_SQ + tid] * inv - mean * mean;   // biased, keras BN
    const float sc = gamma[tid] * rsqrtf(var + 1e-3f);
    sScale[tid] = sc;
    sShift[tid] = beta[tid] - mean * sc;
  }
  __syncthreads();
  if (tid < 256) {
    const int nt = tid >> 6;
    const int lane = tid & 63;
    const int m = lane & 15;
    const int q = lane >> 4;
    const int n = nt * 16 + m;
    u32* Wf = (u32*)(ws + WS_WEF);
#pragma unroll
    for (int ks = 0; ks < 8; ++ks) {
      uint4 pk;
      u32 w_[4];
#pragma unroll
      for (int jj = 0; jj < 4; ++jj) {
        const int k0 = ks * 32 + q * 8 + 2 * jj;
        const u32 lo = f2bf(sScale[k0]     * W1[(size_t)k0 * 64 + n]);
        const u32 hi = f2bf(sScale[k0 + 1] * W1[(size_t)(k0 + 1) * 64 + n]);
        w_[jj] = lo | (hi << 16);
      }
      pk.x = w_[0]; pk.y = w_[1]; pk.z = w_[2]; pk.w = w_[3];
      *(uint4*)(Wf + (size_t)((ks * 4 + nt) * 64 + lane) * 4) = pk;
    }
  }
  // cj[j] = b1[j] + sum_c sShift[c]*W1[c][j], 8-way split over c then LDS combine
  const int j = tid & 63;
  const int part = tid >> 6;            // 0..7
  float p = (part == 0) ? b1[j] : 0.0f;
  for (int c = part * 32; c < part * 32 + 32; ++c)
    p = fmaf(sShift[c], W1[(size_t)c * 64 + j], p);
  sCj[tid] = p;
  __syncthreads();
  if (tid < 64) {
    float a = 0.0f;
#pragma unroll
    for (int k = 0; k < 8; ++k) a += sCj[k * 64 + tid];
    ws[WS_CJ + tid] = a;
  }
}

// ---- pre1t = bf16( x @ We + cj ), chunk-transposed: pre1t[p][j][t0..31] (p=row/32).
//      grid 2048 x 256 thr; wave w handles rows blk*64 + w*16 .. +15. ----
__global__ __launch_bounds__(256) void k_gemm(const float* __restrict__ x,
                                              const float* __restrict__ ws,
                                              u16* __restrict__ pre1t) {
  const int lane = threadIdx.x & 63;
  const int w = threadIdx.x >> 6;
  const int m = lane & 15;
  const int q = lane >> 4;
  const size_t r0 = (size_t)blockIdx.x * 64 + (size_t)w * 16;
  const size_t p = r0 >> 5;                       // chunk index (32 rows/chunk)
  const int tbase = ((int)r0 & 16) + q * 4;       // t-in-chunk for reg 0
  const float* xr = x + (r0 + m) * 256 + q * 8;   // lane's A-frag source row/col
  const u32* Bf = (const u32*)(ws + WS_WEF);

  f32x4 acc[4];
#pragma unroll
  for (int nt = 0; nt < 4; ++nt) acc[nt] = (f32x4){0.f, 0.f, 0.f, 0.f};

#pragma unroll
  for (int ks = 0; ks < 8; ++ks) {
    const float4 xa = *(const float4*)(xr + ks * 32);
    const float4 xb = *(const float4*)(xr + ks * 32 + 4);
    union { short8 v; u32 u[4]; } A;
    A.u[0] = f2bf(xa.x) | ((u32)f2bf(xa.y) << 16);
    A.u[1] = f2bf(xa.z) | ((u32)f2bf(xa.w) << 16);
    A.u[2] = f2bf(xb.x) | ((u32)f2bf(xb.y) << 16);
    A.u[3] = f2bf(xb.z) | ((u32)f2bf(xb.w) << 16);
#pragma unroll
    for (int nt = 0; nt < 4; ++nt) {
      const short8 Bv = *(const short8*)(Bf + (size_t)((ks * 4 + nt) * 64 + lane) * 4);
      acc[nt] = __builtin_amdgcn_mfma_f32_16x16x32_bf16(A.v, Bv, acc[nt], 0, 0, 0);
    }
  }
  // C/D layout (m89): col = nt*16 + m, row-in-16 = q*4 + reg -> t = tbase + reg.
#pragma unroll
  for (int nt = 0; nt < 4; ++nt) {
    const float c = ws[WS_CJ + nt * 16 + m];
    uint2 pk;
    pk.x = (u32)f2bf(acc[nt][0] + c) | ((u32)f2bf(acc[nt][1] + c) << 16);
    pk.y = (u32)f2bf(acc[nt][2] + c) | ((u32)f2bf(acc[nt][3] + c) << 16);
    *(uint2*)(pre1t + p * 2048 + (size_t)(nt * 16 + m) * 32 + tbase) = pk;
  }
}

// ---- chunked scan, rolled loop, no barriers. 4 independent waves / block. ----
__global__ __launch_bounds__(256, 4) void k_scan(const u16* __restrict__ pre1t,
                                                 const float* __restrict__ W1,
                                                 const float* __restrict__ W2,
                                                 const float* __restrict__ b2,
                                                 const float* __restrict__ W3,
                                                 const float* __restrict__ b3,
                                                 float* __restrict__ out) {
  const int tid = threadIdx.x;
  const int lane = tid & 63;
  const int wv = tid >> 6;
  const int p = blockIdx.x * 4 + wv;              // chunk id
  const int m = lane & 31;
  const int half = lane >> 5;
  const int outStart = p * L_CHUNK;

  float Wh[8];
#pragma unroll
  for (int k = 0; k < 8; ++k) Wh[k] = W1[(256 + k) * 64 + lane];
  float W2r[32];
#pragma unroll
  for (int i = 0; i < 32; ++i) W2r[i] = W2[(32 * half + i) * 32 + m];
  const float b2r = b2[m];
  float W3r[8], b3r[8];
#pragma unroll
  for (int n = 0; n < 8; ++n) W3r[n] = W3[m * 8 + n];
#pragma unroll
  for (int n = 0; n < 8; ++n) b3r[n] = b3[n];

  __shared__ __align__(16) float lh1[4][64];

  // lane's pre values: pre1t[p][lane][0..31] = one 64 B line; prev-chunk tail for warm.
  const u16* base2 = pre1t + (size_t)p * 2048 + (size_t)lane * 32;

  float h[8], osv[8];
#pragma unroll
  for (int n = 0; n < 8; ++n) { h[n] = 0.0f; osv[n] = 0.0f; }

  auto step = [&](float pf, int rel) {
    float a0 = pf, a1 = 0.0f;
#pragma unroll
    for (int k = 0; k < 4; ++k) {                 // a = pre + Wh^T h (2 chains)
      a0 = fmaf(h[2 * k],     Wh[2 * k],     a0);
      a1 = fmaf(h[2 * k + 1], Wh[2 * k + 1], a1);
    }
    const float h1 = fmaxf(a0 + a1, 0.0f);
    // single-wave LDS round-trip: per-wave DS ordering + compiler pin
    __builtin_amdgcn_wave_barrier();
    lh1[wv][lane] = h1;
    __builtin_amdgcn_wave_barrier();
    const float4* qv = (const float4*)(lh1[wv] + half * 32);
    float c0 = 0, c1 = 0, c2 = 0, c3 = 0;
#pragma unroll
    for (int r = 0; r < 8; ++r) {                 // half-sum of h1@W2 column m
      const float4 v = qv[r];
      c0 = fmaf(v.x, W2r[4 * r + 0], c0);
      c1 = fmaf(v.y, W2r[4 * r + 1], c1);
      c2 = fmaf(v.z, W2r[4 * r + 2], c2);
      c3 = fmaf(v.w, W2r[4 * r + 3], c3);
    }
    const float part = (c0 + c1) + (c2 + c3);
    const float h2 = fmaxf(part + __shfl_xor(part, 32, 64) + b2r, 0.0f);
    float o[8];
#pragma unroll
    for (int n = 0; n < 8; ++n) o[n] = h2 * W3r[n];
#pragma unroll
    for (int n = 0; n < 8; ++n) o[n] += dpp_take<0xB1>(o[n]);   // quad_perm xor1
#pragma unroll
    for (int n = 0; n < 8; ++n) o[n] += dpp_take<0x4E>(o[n]);   // quad_perm xor2
#pragma unroll
    for (int n = 0; n < 8; ++n) o[n] += dpp_take<0x141>(o[n]);  // row_half_mirror (8)
#pragma unroll
    for (int n = 0; n < 8; ++n) o[n] += dpp_take<0x140>(o[n]);  // row_mirror (16)
#pragma unroll
    for (int n = 0; n < 8; ++n) o[n] += swz_xor16(o[n]);        // xor16 within 32
#pragma unroll
    for (int n = 0; n < 8; ++n) h[n] = o[n] + b3r[n];
    const bool mine = (lane == rel);              // rel<0 -> never true
#pragma unroll
    for (int n = 0; n < 8; ++n) osv[n] = mine ? h[n] : osv[n];
  };

  auto ldpf = [&](int rel) -> uint2 {             // rel<0 -> prev chunk tail (-2048+32)
    return *(const uint2*)(base2 + rel + ((rel < 0) ? -2016 : 0));
  };

  int t = (p > 0) ? -WARM : 0;
  uint2 cur = ldpf(t);
  for (; t < L_CHUNK; t += 4) {
    int tn = t + 4;
    if (tn > L_CHUNK - 4) tn = L_CHUNK - 4;       // clamped prefetch
    const uint2 nxt = ldpf(tn);
    const u32 w0 = cur.x, w1 = cur.y;
    step(__uint_as_float(w0 << 16),          t);
    step(__uint_as_float(w0 & 0xFFFF0000u),  t + 1);
    step(__uint_as_float(w1 << 16),          t + 2);
    step(__uint_as_float(w1 & 0xFFFF0000u),  t + 3);
    cur = nxt;
  }

  if (lane < 32) {                                // coalesced epilogue store
    float4* dst = (float4*)(out + (size_t)(outStart + lane) * 8);
    dst[0] = make_float4(osv[0], osv[1], osv[2], osv[3]);
    dst[1] = make_float4(osv[4], osv[5], osv[6], osv[7]);
  }
}

extern "C" void kernel_launch(void* const* d_in, const int* in_sizes, int n_in,
                              void* d_out, int out_size, void* d_ws, size_t ws_size,
                              hipStream_t stream) {
  (void)in_sizes; (void)n_in; (void)out_size;
  const float* x     = (const float*)d_in[0];
  const float* gamma = (const float*)d_in[1];
  const float* beta  = (const float*)d_in[2];
  const float* W1    = (const float*)d_in[3];
  const float* b1    = (const float*)d_in[4];
  const float* W2    = (const float*)d_in[5];
  const float* b2    = (const float*)d_in[6];
  const float* W3    = (const float*)d_in[7];
  const float* b3    = (const float*)d_in[8];
  float* out = (float*)d_out;
  float* ws  = (float*)d_ws;
  u16* pre1t = (u16*)((char*)d_ws + WS_PRE_BYTES);

  if (ws_size < WS_NEED) {               // diagnosable failure: absmax ~12345
    k_sentinel<<<1, 64, 0, stream>>>(out);
    return;
  }
  k_zero <<<1,    512, 0, stream>>>(ws);
  k_stats<<<1024, 256, 0, stream>>>(x, ws);
  k_prep <<<1,    512, 0, stream>>>(gamma, beta, W1, b1, ws);
  k_gemm <<<2048, 256, 0, stream>>>(x, ws, pre1t);
  k_scan <<<NCHUNK / 4, 256, 0, stream>>>(pre1t, W1, W2, b2, W3, b3, out);
}

// Round 6
// 281.052 us; speedup vs baseline: 1.0934x; 1.0419x over previous
//
#include <hip/hip_runtime.h>
#include <hip/hip_bf16.h>

typedef unsigned short u16;
typedef unsigned int   u32;
typedef __attribute__((ext_vector_type(8))) short short8;   // 8 bf16 (4 VGPRs)
typedef __attribute__((ext_vector_type(4))) float f32x4;

#define T_ROWS   131072
#define L_CHUNK  16
#define WARM     8             // rho<=0.34 -> 0.34^8 ~ 1.8e-4; x0.5 ~ 9e-5 boundary error
#define NBATCH   (T_ROWS / (16 * L_CHUNK))   // 512 waves, 16 chunks each

// ws layout (float offsets)
#define WS_SUM   0             // 256 f
#define WS_SQ    256           // 256 f
#define WS_CJ    512           // 64 f  (b1 + shift@W1 folded)
#define WS_WEF   576           // 8192 u32: We bf16 in MFMA B-frag order [ks*4+nt][lane][j(8)]
#define WS_PRE_BYTES ((size_t)(WS_WEF + 8192) * 4)            // 35072 B
#define WS_NEED  (WS_PRE_BYTES + (size_t)T_ROWS * 64 * 2)     // + pre1 bf16 ~16.8 MB

__device__ __forceinline__ u16 f2bf(float f) {   // RNE float->bf16
  u32 u = __float_as_uint(f);
  u += 0x7FFFu + ((u >> 16) & 1u);
  return (u16)(u >> 16);
}
__device__ __forceinline__ u32 packbf(float a, float b) {
  return (u32)f2bf(a) | ((u32)f2bf(b) << 16);
}
__device__ __forceinline__ float bfl(u32 u) { return __uint_as_float(u << 16); }
__device__ __forceinline__ float bfh(u32 u) { return __uint_as_float(u & 0xFFFF0000u); }

__global__ void k_zero(float* ws) { ws[threadIdx.x] = 0.0f; }   // <<<1,512>>>

__global__ void k_sentinel(float* out) { out[threadIdx.x] = 12345.0f; }

// ---- column mean / sumsq over x[131072][256], grid 1024 x 256 thr ----
__global__ __launch_bounds__(256) void k_stats(const float* __restrict__ x,
                                               float* __restrict__ ws) {
  __shared__ float lsum[1024];
  __shared__ float lsq[1024];
  const int tid = threadIdx.x;
  const int lane = tid & 63;
  const int w = tid >> 6;
  const int c = lane * 4;
  float s0 = 0, s1 = 0, s2 = 0, s3 = 0;
  float q0 = 0, q1 = 0, q2 = 0, q3 = 0;
  const size_t rbase = (size_t)blockIdx.x * 128;
#pragma unroll 4
  for (int i = w; i < 128; i += 4) {
    const float4 v = *(const float4*)(x + (rbase + i) * 256 + c);
    s0 += v.x; s1 += v.y; s2 += v.z; s3 += v.w;
    q0 = fmaf(v.x, v.x, q0); q1 = fmaf(v.y, v.y, q1);
    q2 = fmaf(v.z, v.z, q2); q3 = fmaf(v.w, v.w, q3);
  }
  lsum[w * 256 + c + 0] = s0; lsum[w * 256 + c + 1] = s1;
  lsum[w * 256 + c + 2] = s2; lsum[w * 256 + c + 3] = s3;
  lsq [w * 256 + c + 0] = q0; lsq [w * 256 + c + 1] = q1;
  lsq [w * 256 + c + 2] = q2; lsq [w * 256 + c + 3] = q3;
  __syncthreads();
  const float ts = lsum[tid] + lsum[256 + tid] + lsum[512 + tid] + lsum[768 + tid];
  const float tq = lsq [tid] + lsq [256 + tid] + lsq [512 + tid] + lsq [768 + tid];
  atomicAdd(ws + WS_SUM + tid, ts);
  atomicAdd(ws + WS_SQ  + tid, tq);
}

// ---- fold BN into weights. Emits We = scale*W1[:256] in MFMA B-frag order. 512 thr. ----
__global__ __launch_bounds__(512) void k_prep(const float* __restrict__ gamma,
                                              const float* __restrict__ beta,
                                              const float* __restrict__ W1,
                                              const float* __restrict__ b1,
                                              float* __restrict__ ws) {
  __shared__ float sScale[256];
  __shared__ float sShift[256];
  __shared__ float sCj[512];
  const int tid = threadIdx.x;
  if (tid < 256) {
    const float inv = 1.0f / (float)T_ROWS;
    const float mean = ws[WS_SUM + tid] * inv;
    const float var  = ws[WS_SQ + tid] * inv - mean * mean;   // biased, keras BN
    const float sc = gamma[tid] * rsqrtf(var + 1e-3f);
    sScale[tid] = sc;
    sShift[tid] = beta[tid] - mean * sc;
  }
  __syncthreads();
  if (tid < 256) {
    const int nt = tid >> 6;
    const int lane = tid & 63;
    const int m = lane & 15;
    const int q = lane >> 4;
    const int n = nt * 16 + m;
    u32* Wf = (u32*)(ws + WS_WEF);
#pragma unroll
    for (int ks = 0; ks < 8; ++ks) {
      uint4 pk;
      u32 w_[4];
#pragma unroll
      for (int jj = 0; jj < 4; ++jj) {
        const int k0 = ks * 32 + q * 8 + 2 * jj;
        const u32 lo = f2bf(sScale[k0]     * W1[(size_t)k0 * 64 + n]);
        const u32 hi = f2bf(sScale[k0 + 1] * W1[(size_t)(k0 + 1) * 64 + n]);
        w_[jj] = lo | (hi << 16);
      }
      pk.x = w_[0]; pk.y = w_[1]; pk.z = w_[2]; pk.w = w_[3];
      *(uint4*)(Wf + (size_t)((ks * 4 + nt) * 64 + lane) * 4) = pk;
    }
  }
  // cj[j] = b1[j] + sum_c sShift[c]*W1[c][j], 8-way split over c then LDS combine
  const int j = tid & 63;
  const int part = tid >> 6;            // 0..7
  float p = (part == 0) ? b1[j] : 0.0f;
  for (int c = part * 32; c < part * 32 + 32; ++c)
    p = fmaf(sShift[c], W1[(size_t)c * 64 + j], p);
  sCj[tid] = p;
  __syncthreads();
  if (tid < 64) {
    float a = 0.0f;
#pragma unroll
    for (int k = 0; k < 8; ++k) a += sCj[k * 64 + tid];
    ws[WS_CJ + tid] = a;
  }
}

// ---- pre1 = bf16( x @ We + cj ), plain row-major [t][64].  grid 2048 x 256 thr. ----
__global__ __launch_bounds__(256) void k_gemm(const float* __restrict__ x,
                                              const float* __restrict__ ws,
                                              u16* __restrict__ pre1) {
  const int lane = threadIdx.x & 63;
  const int w = threadIdx.x >> 6;
  const int m = lane & 15;
  const int q = lane >> 4;
  const size_t r0 = (size_t)blockIdx.x * 64 + (size_t)w * 16;
  const float* xr = x + (r0 + m) * 256 + q * 8;   // lane's A-frag source row/col
  const u32* Bf = (const u32*)(ws + WS_WEF);

  f32x4 acc[4];
#pragma unroll
  for (int nt = 0; nt < 4; ++nt) acc[nt] = (f32x4){0.f, 0.f, 0.f, 0.f};

#pragma unroll
  for (int ks = 0; ks < 8; ++ks) {
    const float4 xa = *(const float4*)(xr + ks * 32);
    const float4 xb = *(const float4*)(xr + ks * 32 + 4);
    union { short8 v; u32 u[4]; } A;
    A.u[0] = packbf(xa.x, xa.y);
    A.u[1] = packbf(xa.z, xa.w);
    A.u[2] = packbf(xb.x, xb.y);
    A.u[3] = packbf(xb.z, xb.w);
#pragma unroll
    for (int nt = 0; nt < 4; ++nt) {
      const short8 Bv = *(const short8*)(Bf + (size_t)((ks * 4 + nt) * 64 + lane) * 4);
      acc[nt] = __builtin_amdgcn_mfma_f32_16x16x32_bf16(A.v, Bv, acc[nt], 0, 0, 0);
    }
  }
  // C/D layout: col = nt*16 + m, row = r0 + q*4 + reg  (session-verified)
#pragma unroll
  for (int nt = 0; nt < 4; ++nt) {
    const float c = ws[WS_CJ + nt * 16 + m];
#pragma unroll
    for (int reg = 0; reg < 4; ++reg)
      pre1[(r0 + q * 4 + reg) * 64 + nt * 16 + m] = f2bf(acc[nt][reg] + c);
  }
}

// ---- MFMA-batched scan: 1 wave = 16 chunks in lockstep, transposed layers.
//      D[l][m=chunk] via mfma_16x16x32; feedback via 16x8 LDS tile. ----
struct P4 { uint2 v[4]; };

__global__ __launch_bounds__(64) void k_scan(const u16* __restrict__ pre1,
                                             const float* __restrict__ W1,
                                             const float* __restrict__ W2,
                                             const float* __restrict__ b2,
                                             const float* __restrict__ W3,
                                             const float* __restrict__ b3,
                                             float* __restrict__ out) {
  const int lane = threadIdx.x;
  const int q   = lane >> 4;
  const int l15 = lane & 15;
  const int Bk  = blockIdx.x;
  const bool isB0 = (Bk == 0);
  const int c = Bk * 16 + l15;          // this lane's chunk (N-col m of the MFMAs)

  typedef union { short8 v; u32 u[4]; uint4 u4; } Frag;

  // A1[t4]: A[n1=16*t4+l15][k=e] = W1[256+e][n1]  (k<8 -> only quad 0 nonzero)
  Frag A1[4];
#pragma unroll
  for (int t4 = 0; t4 < 4; ++t4)
#pragma unroll
    for (int i = 0; i < 4; ++i) {
      u32 pk = 0;
      if (q == 0) {
        const int n1 = 16 * t4 + l15;
        pk = packbf(W1[(256 + 2 * i) * 64 + n1], W1[(256 + 2 * i + 1) * 64 + n1]);
      }
      A1[t4].u[i] = pk;
    }
  // A2[m2][hf]: A[n2=16*m2+l15][k1=32*hf+8q+e] = W2[k1][n2]
  Frag A2[2][2];
#pragma unroll
  for (int m2 = 0; m2 < 2; ++m2)
#pragma unroll
    for (int hf = 0; hf < 2; ++hf)
#pragma unroll
      for (int i = 0; i < 4; ++i) {
        const int n2 = 16 * m2 + l15;
        const int k0 = 32 * hf + 8 * q + 2 * i;
        A2[m2][hf].u[i] = packbf(W2[k0 * 32 + n2], W2[(k0 + 1) * 32 + n2]);
      }
  // A3: A[o=l15][k2=8q+e] = W3[k2][o]  (rows o>=8 zeroed; their D rows are discarded)
  Frag A3;
  {
    const int o = l15 & 7;
#pragma unroll
    for (int i = 0; i < 4; ++i) {
      const int k0 = 8 * q + 2 * i;
      const u32 pk = packbf(W3[k0 * 8 + o], W3[(k0 + 1) * 8 + o]);
      A3.u[i] = (l15 < 8) ? pk : 0;
    }
  }
  // biases as MFMA C operands (row r = 4q+reg)
  f32x4 b2c[2], b3c;
#pragma unroll
  for (int m2 = 0; m2 < 2; ++m2) {
    const float4 t = *(const float4*)(b2 + 16 * m2 + 4 * q);
    b2c[m2] = (f32x4){t.x, t.y, t.z, t.w};
  }
  {
    const float4 t = *(const float4*)(b3 + 4 * (q & 1));   // q>=2 rows discarded
    b3c = (f32x4){t.x, t.y, t.z, t.w};
  }

  // LDS tiles (row strides padded vs 32-bank aliasing; 16B-aligned rows)
  __shared__ __align__(16) u16 L1[16 * 88];   // h1: [m][k1], stride 88
  __shared__ __align__(16) u16 L2[16 * 40];   // h2: [m][k2], stride 40
  __shared__ __align__(16) u16 L3[16 * 8];    // h : [m][o],  stride 8
  u16*       l1w = &L1[l15 * 88 + 4 * q];     // + 16*t4, b64 writes
  const u16* l1r = &L1[l15 * 88 + 8 * q];     // + 32*hf, b128 reads
  u16*       l2w = &L2[l15 * 40 + 4 * q];     // + 16*m2
  const u16* l2r = &L2[l15 * 40 + 8 * q];
  u16*       l3w = &L3[l15 * 8 + 4 * q];      // q<2 only
  const u16* l3r = &L3[l15 * 8];

  if (lane < 16) *(uint4*)&L3[lane * 8] = make_uint4(0, 0, 0, 0);
  __builtin_amdgcn_wave_barrier();

  // pre loads: row-major pre1[t][n]; lane reads its chunk's row, 4x b64 (cols 16*t4+4q)
  auto ldpre = [&](int t) {
    P4 r;
    int row = c * 16 + t;
    if (row < 0) row = 0;                     // only B0/chunk0 warm; discarded via kill
    const u16* pr = pre1 + (size_t)row * 64 + 4 * q;
#pragma unroll
    for (int t4 = 0; t4 < 4; ++t4) r.v[t4] = *(const uint2*)(pr + 16 * t4);
    return r;
  };

  uint4 s0, s1, s2, s3;                       // save shift-queue (4 steps/lane)
  s0 = s1 = s2 = s3 = make_uint4(0, 0, 0, 0);

  P4 pc = ldpre(-WARM);
#pragma unroll 2
  for (int t = -WARM; t < L_CHUNK; ++t) {
    const int tn = (t + 1 < L_CHUNK - 1) ? t + 1 : L_CHUNK - 1;
    const P4 pn = ldpre(tn);                  // prefetch next step's pre

    // feedback read: h(t-1) for all 16 chunks
    Frag hv; hv.u4 = *(const uint4*)l3r;
    // save h(t-1) if it's one of this lane's output steps (shift queue)
    const bool mt = (t - 1 >= 0) && (q == ((t - 1) >> 2));
    s0 = mt ? s1 : s0; s1 = mt ? s2 : s1; s2 = mt ? s3 : s2; s3 = mt ? hv.u4 : s3;

    Frag b1;
#pragma unroll
    for (int i = 0; i < 4; ++i) b1.u[i] = (q == 0) ? hv.u[i] : 0;
    if (t == 0 && isB0) {                     // chunk 0 starts exactly from h=0
#pragma unroll
      for (int i = 0; i < 4; ++i) b1.u[i] = (l15 == 0) ? 0 : b1.u[i];
    }
    __builtin_amdgcn_wave_barrier();

    // layer 1: D1[n1][m] = Wh^T h + pre  (C carries pre), relu, pack to L1[m][k1]
#pragma unroll
    for (int t4 = 0; t4 < 4; ++t4) {
      const uint2 pp = pc.v[t4];
      const f32x4 C = (f32x4){bfl(pp.x), bfh(pp.x), bfl(pp.y), bfh(pp.y)};
      const f32x4 d = __builtin_amdgcn_mfma_f32_16x16x32_bf16(A1[t4].v, b1.v, C, 0, 0, 0);
      uint2 wv;
      wv.x = packbf(fmaxf(d[0], 0.f), fmaxf(d[1], 0.f));
      wv.y = packbf(fmaxf(d[2], 0.f), fmaxf(d[3], 0.f));
      *(uint2*)(l1w + 16 * t4) = wv;
    }
    __builtin_amdgcn_wave_barrier();
    short8 h1f0 = *(const short8*)(l1r);
    short8 h1f1 = *(const short8*)(l1r + 32);
    __builtin_amdgcn_wave_barrier();

    // layer 2: D2[n2][m] = W2^T h1 + b2, relu, pack to L2[m][k2]
#pragma unroll
    for (int m2 = 0; m2 < 2; ++m2) {
      f32x4 d = __builtin_amdgcn_mfma_f32_16x16x32_bf16(A2[m2][0].v, h1f0, b2c[m2], 0, 0, 0);
      d = __builtin_amdgcn_mfma_f32_16x16x32_bf16(A2[m2][1].v, h1f1, d, 0, 0, 0);
      uint2 wv;
      wv.x = packbf(fmaxf(d[0], 0.f), fmaxf(d[1], 0.f));
      wv.y = packbf(fmaxf(d[2], 0.f), fmaxf(d[3], 0.f));
      *(uint2*)(l2w + 16 * m2) = wv;
    }
    __builtin_amdgcn_wave_barrier();
    short8 h2f = *(const short8*)l2r;
    __builtin_amdgcn_wave_barrier();

    // layer 3: D3[o][m] = W3^T h2 + b3 -> h(t), pack to L3[m][o]
    const f32x4 d3 = __builtin_amdgcn_mfma_f32_16x16x32_bf16(A3.v, h2f, b3c, 0, 0, 0);
    if (q < 2) {
      uint2 wv;
      wv.x = packbf(d3[0], d3[1]);
      wv.y = packbf(d3[2], d3[3]);
      *(uint2*)l3w = wv;
    }
    __builtin_amdgcn_wave_barrier();
    pc = pn;
  }
  {                                           // h(15) final save (q==3, slot 3)
    Frag hv; hv.u4 = *(const uint4*)l3r;
    const bool mt = (q == 3);
    s0 = mt ? s1 : s0; s1 = mt ? s2 : s1; s2 = mt ? s3 : s2; s3 = mt ? hv.u4 : s3;
  }

  // epilogue: lane(q,l15) owns chunk c rows 4q..4q+3 -> out[c*16 + 4q + tt][0..8)
  const size_t rowBase = (size_t)c * L_CHUNK + 4 * q;
  const uint4 sv[4] = {s0, s1, s2, s3};
#pragma unroll
  for (int tt = 0; tt < 4; ++tt) {
    const uint4 s = sv[tt];
    float4* dst = (float4*)(out + (rowBase + tt) * 8);
    dst[0] = make_float4(bfl(s.x), bfh(s.x), bfl(s.y), bfh(s.y));
    dst[1] = make_float4(bfl(s.z), bfh(s.z), bfl(s.w), bfh(s.w));
  }
}

extern "C" void kernel_launch(void* const* d_in, const int* in_sizes, int n_in,
                              void* d_out, int out_size, void* d_ws, size_t ws_size,
                              hipStream_t stream) {
  (void)in_sizes; (void)n_in; (void)out_size;
  const float* x     = (const float*)d_in[0];
  const float* gamma = (const float*)d_in[1];
  const float* beta  = (const float*)d_in[2];
  const float* W1    = (const float*)d_in[3];
  const float* b1    = (const float*)d_in[4];
  const float* W2    = (const float*)d_in[5];
  const float* b2    = (const float*)d_in[6];
  const float* W3    = (const float*)d_in[7];
  const float* b3    = (const float*)d_in[8];
  float* out = (float*)d_out;
  float* ws  = (float*)d_ws;
  u16* pre1  = (u16*)((char*)d_ws + WS_PRE_BYTES);

  if (ws_size < WS_NEED) {               // diagnosable failure: absmax ~12345
    k_sentinel<<<1, 64, 0, stream>>>(out);
    return;
  }
  k_zero <<<1,     512, 0, stream>>>(ws);
  k_stats<<<1024,  256, 0, stream>>>(x, ws);
  k_prep <<<1,     512, 0, stream>>>(gamma, beta, W1, b1, ws);
  k_gemm <<<2048,  256, 0, stream>>>(x, ws, pre1);
  k_scan <<<NBATCH, 64, 0, stream>>>(pre1, W1, W2, b2, W3, b3, out);
}